// Round 1
// baseline (97.467 us; speedup 1.0000x reference)
//
#include <hip/hip_runtime.h>

#define TN 6
#define CFC 256
#define HFC 32
#define WFC 88
#define HWC (HFC * WFC)   // 2816
#define EPSF 1e-5f

// ---------------- transpose (6,256,32,88) -> (6,32,88,256) ----------------
__global__ __launch_bounds__(256) void proj_transpose_kernel(
    const float* __restrict__ src, float* __restrict__ dst)
{
    __shared__ float tile[32][33];
    const int n   = blockIdx.z;
    const int hw0 = blockIdx.x * 32;   // 88 tiles over 2816
    const int c0  = blockIdx.y * 32;   // 8 tiles over 256
    const float* s = src + (size_t)n * (CFC * HWC);
    float*       d = dst + (size_t)n * (CFC * HWC);
    const int tx = threadIdx.x, ty = threadIdx.y;

#pragma unroll
    for (int k = 0; k < 32; k += 8)
        tile[ty + k][tx] = s[(size_t)(c0 + ty + k) * HWC + hw0 + tx];
    __syncthreads();
#pragma unroll
    for (int k = 0; k < 32; k += 8)
        d[(size_t)(hw0 + ty + k) * CFC + c0 + tx] = tile[tx][ty + k];
}

// ---------------- main fused kernel: one block per output cell ----------------
// TR=true: feat is channel-last (6,32,88,256) in ws. TR=false: original layout.
template <bool TR>
__global__ __launch_bounds__(256) void proj_fuse_kernel(
    const float* __restrict__ points,
    const float* __restrict__ feat,
    const float* __restrict__ lid2img,
    const float* __restrict__ ego2lid,
    const float* __restrict__ img2lid,
    const int*   __restrict__ img_h,
    const int*   __restrict__ img_w,
    float* __restrict__ out)
{
    __shared__ float sM[TN][16];   // lid2img @ ego2lid
    __shared__ float sB[TN][16];   // img2lid
    __shared__ float spts[2][3];

    const int t    = threadIdx.x;          // channel
    const int i    = blockIdx.y;           // BW index
    const int j    = blockIdx.x;           // BH index
    const int cell = i * 128 + j;

    if (t < 96) {
        const int n = t >> 4, e = t & 15, r = e >> 2, cc = e & 3;
        float acc = 0.f;
#pragma unroll
        for (int k = 0; k < 4; ++k)
            acc += lid2img[n * 16 + r * 4 + k] * ego2lid[n * 16 + k * 4 + cc];
        sM[n][e] = acc;
    } else if (t < 192) {
        const int q = t - 96;
        sB[q >> 4][q & 15] = img2lid[q];
    } else if (t < 198) {
        const int q = t - 192;
        spts[q / 3][q % 3] = points[cell * 6 + q];
    }
    __syncthreads();

    const float wscale = (float)WFC / (float)img_w[0];
    const float hscale = (float)HFC / (float)img_h[0];

    float feat_acc   = 0.f;
    float xyz_acc[3] = {0.f, 0.f, 0.f};

#pragma unroll
    for (int cp = 0; cp < 2; ++cp) {
        const float px = spts[cp][0], py = spts[cp][1], pz = spts[cp][2];
        float fsum    = 0.f;
        float back[4] = {0.f, 0.f, 0.f, 0.f};
        int   cnt     = 0;

#pragma unroll
        for (int n = 0; n < TN; ++n) {
            float pr[4];
#pragma unroll
            for (int r = 0; r < 4; ++r)
                pr[r] = sM[n][r * 4 + 0] * px + sM[n][r * 4 + 1] * py +
                        sM[n][r * 4 + 2] * pz + sM[n][r * 4 + 3];
            const float depth = pr[2];
            const float dmax  = fmaxf(depth, EPSF);
            const float u = pr[0] / dmax * wscale;
            const float v = pr[1] / dmax * hscale;
            const bool valid = (depth > EPSF) && (u >= 0.f) && (u <= (float)(WFC - 1)) &&
                               (v >= 0.f) && (v <= (float)(HFC - 1));
            if (valid) {
                ++cnt;
                const float fx0 = fminf(fmaxf(floorf(u), 0.f), (float)(WFC - 2));
                const float fy0 = fminf(fmaxf(floorf(v), 0.f), (float)(HFC - 2));
                const int x0 = (int)fx0, y0 = (int)fy0;
                const float wx = fminf(fmaxf(u - fx0, 0.f), 1.f);
                const float wy = fminf(fmaxf(v - fy0, 0.f), 1.f);
                float f00, f01, f10, f11;
                if (TR) {
                    const float* bp = feat + ((size_t)((n * HFC + y0) * WFC + x0)) * CFC + t;
                    f00 = bp[0];
                    f01 = bp[CFC];
                    f10 = bp[WFC * CFC];
                    f11 = bp[WFC * CFC + CFC];
                } else {
                    const float* bp = feat + ((size_t)(n * CFC + t) * HFC + y0) * WFC + x0;
                    f00 = bp[0];
                    f01 = bp[1];
                    f10 = bp[WFC];
                    f11 = bp[WFC + 1];
                }
                fsum += (1.f - wy) * ((1.f - wx) * f00 + wx * f01) +
                        wy * ((1.f - wx) * f10 + wx * f11);
#pragma unroll
                for (int r = 0; r < 4; ++r)
                    back[r] += sB[n][r * 4 + 0] * pr[0] + sB[n][r * 4 + 1] * pr[1] +
                               sB[n][r * 4 + 2] * pr[2] + sB[n][r * 4 + 3] * pr[3];
            }
        }

        const float cntf = fmaxf((float)cnt, 1.f);
        fsum = fsum / cntf;
        feat_acc += fsum;

        const float wv = back[3] / cntf;
        const float dw = (fabsf(wv) < EPSF) ? 1.f : wv;
#pragma unroll
        for (int r = 0; r < 3; ++r)
            xyz_acc[r] += (back[r] / cntf) / dw;
    }

    float* op = out + (size_t)cell * (3 + CFC);
    op[3 + t] = feat_acc * 0.5f;
    if (t < 3) op[t] = xyz_acc[t] * 0.5f;
}

extern "C" void kernel_launch(void* const* d_in, const int* in_sizes, int n_in,
                              void* d_out, int out_size, void* d_ws, size_t ws_size,
                              hipStream_t stream)
{
    const float* points   = (const float*)d_in[0];
    const float* img_feat = (const float*)d_in[1];
    const float* lid2img  = (const float*)d_in[2];
    const float* ego2lid  = (const float*)d_in[3];
    const float* img2lid  = (const float*)d_in[4];
    const int*   img_h    = (const int*)d_in[5];
    const int*   img_w    = (const int*)d_in[6];
    float*       out      = (float*)d_out;

    const size_t need = (size_t)TN * CFC * HWC * sizeof(float);  // 17.3 MB

    dim3 fuse_grid(128, 128);

    if (ws_size >= need) {
        float* featT = (float*)d_ws;
        dim3 tg(HWC / 32, CFC / 32, TN);  // (88, 8, 6)
        proj_transpose_kernel<<<tg, dim3(32, 8), 0, stream>>>(img_feat, featT);
        proj_fuse_kernel<true><<<fuse_grid, 256, 0, stream>>>(
            points, featT, lid2img, ego2lid, img2lid, img_h, img_w, out);
    } else {
        proj_fuse_kernel<false><<<fuse_grid, 256, 0, stream>>>(
            points, img_feat, lid2img, ego2lid, img2lid, img_h, img_w, out);
    }
}

// Round 2
// 28.495 us; speedup vs baseline: 3.4204x; 3.4204x over previous
//
#include <hip/hip_runtime.h>

#define TN 6
#define CFC 256
#define HFC 32
#define WFC 88
#define HWC (HFC * WFC)   // 2816
#define EPSF 1e-5f
#define OUTC (3 + CFC)    // 259

// ---------------- transpose (6,256,32,88) -> (6,32,88,256) ----------------
__global__ __launch_bounds__(256) void proj_transpose_kernel(
    const float* __restrict__ src, float* __restrict__ dst)
{
    __shared__ float tile[32][33];
    const int n   = blockIdx.z;
    const int hw0 = blockIdx.x * 32;   // 88 tiles over 2816
    const int c0  = blockIdx.y * 32;   // 8 tiles over 256
    const float* s = src + (size_t)n * (CFC * HWC);
    float*       d = dst + (size_t)n * (CFC * HWC);
    const int tx = threadIdx.x, ty = threadIdx.y;

#pragma unroll
    for (int k = 0; k < 32; k += 8)
        tile[ty + k][tx] = s[(size_t)(c0 + ty + k) * HWC + hw0 + tx];
    __syncthreads();
#pragma unroll
    for (int k = 0; k < 32; k += 8)
        d[(size_t)(hw0 + ty + k) * CFC + c0 + tx] = tile[tx][ty + k];
}

// ---------------- fused kernel: ONE WAVE per output cell ----------------
// Lanes 0..11 do all scalar projection math (one (point,camera) slot each),
// valid slots are compacted into LDS; then all 64 lanes gather 4 channels
// each (float4) over only the valid slots.
template <bool TR>
__global__ __launch_bounds__(64) void proj_fuse_kernel(
    const float* __restrict__ points,
    const float* __restrict__ feat,
    const float* __restrict__ lid2img,
    const float* __restrict__ ego2lid,
    const float* __restrict__ img2lid,
    const int*   __restrict__ img_h,
    const int*   __restrict__ img_w,
    float* __restrict__ out)
{
    __shared__ int    sOff[16];
    __shared__ float4 sW[16];
    __shared__ float  sBack[12][4];

    const int t    = threadIdx.x;   // 0..63
    const int cell = blockIdx.x;    // 0..16383

    // ---- Phase A: lanes 0..11 compute per-slot projections ----
    bool  valid = false;
    int   off   = 0;
    float w00 = 0.f, w01 = 0.f, w10 = 0.f, w11 = 0.f;
    float bk[4] = {0.f, 0.f, 0.f, 0.f};

    if (t < 12) {
        const int cp = t / 6, n = t % 6;
        const float px = points[cell * 6 + cp * 3 + 0];
        const float py = points[cell * 6 + cp * 3 + 1];
        const float pz = points[cell * 6 + cp * 3 + 2];

        // M = lid2img[n] @ ego2lid[n], then pr = M @ [px,py,pz,1]
        float pr[4];
#pragma unroll
        for (int r = 0; r < 4; ++r) {
            float m0 = 0.f, m1 = 0.f, m2 = 0.f, m3 = 0.f;
#pragma unroll
            for (int k = 0; k < 4; ++k) {
                const float l = lid2img[n * 16 + r * 4 + k];
                m0 += l * ego2lid[n * 16 + k * 4 + 0];
                m1 += l * ego2lid[n * 16 + k * 4 + 1];
                m2 += l * ego2lid[n * 16 + k * 4 + 2];
                m3 += l * ego2lid[n * 16 + k * 4 + 3];
            }
            pr[r] = m0 * px + m1 * py + m2 * pz + m3;
        }

        const float depth  = pr[2];
        const float dmax   = fmaxf(depth, EPSF);
        const float wscale = (float)WFC / (float)img_w[0];
        const float hscale = (float)HFC / (float)img_h[0];
        const float u = pr[0] / dmax * wscale;
        const float v = pr[1] / dmax * hscale;
        valid = (depth > EPSF) && (u >= 0.f) && (u <= (float)(WFC - 1)) &&
                (v >= 0.f) && (v <= (float)(HFC - 1));
        if (valid) {
            const float fx0 = fminf(fmaxf(floorf(u), 0.f), (float)(WFC - 2));
            const float fy0 = fminf(fmaxf(floorf(v), 0.f), (float)(HFC - 2));
            const int   x0  = (int)fx0, y0 = (int)fy0;
            const float wx  = fminf(fmaxf(u - fx0, 0.f), 1.f);
            const float wy  = fminf(fmaxf(v - fy0, 0.f), 1.f);
            w00 = (1.f - wy) * (1.f - wx);
            w01 = (1.f - wy) * wx;
            w10 = wy * (1.f - wx);
            w11 = wy * wx;
            if (TR)
                off = ((n * HFC + y0) * WFC + x0) * CFC;          // float index, ch-last
            else
                off = n * CFC * HWC + y0 * WFC + x0;               // + ch*HWC later
#pragma unroll
            for (int r = 0; r < 4; ++r)
                bk[r] = img2lid[n * 16 + r * 4 + 0] * pr[0] +
                        img2lid[n * 16 + r * 4 + 1] * pr[1] +
                        img2lid[n * 16 + r * 4 + 2] * pr[2] +
                        img2lid[n * 16 + r * 4 + 3] * pr[3];
        }
    }

    const unsigned long long m = __ballot(valid);
    const int cnt0 = __popcll(m & 0x03Full);
    const int cnt1 = __popcll(m & 0xFC0ull);

    if (valid) {
        const int   pos = __popcll(m & ((1ull << t) - 1ull));
        const float scl = 0.5f / fmaxf((float)(t < 6 ? cnt0 : cnt1), 1.f);
        sOff[pos] = off;
        sW[pos]   = make_float4(w00 * scl, w01 * scl, w10 * scl, w11 * scl);
    }
    if (t < 12) {
        sBack[t][0] = bk[0]; sBack[t][1] = bk[1];
        sBack[t][2] = bk[2]; sBack[t][3] = bk[3];
    }
    __syncthreads();

    // ---- xyz (lane 0, trivial serial work) ----
    if (t == 0) {
        float xyz[3] = {0.f, 0.f, 0.f};
#pragma unroll
        for (int cp = 0; cp < 2; ++cp) {
            const float cntf = fmaxf((float)(cp == 0 ? cnt0 : cnt1), 1.f);
            float b[4];
#pragma unroll
            for (int r = 0; r < 4; ++r) {
                float s = 0.f;
#pragma unroll
                for (int n = 0; n < TN; ++n) s += sBack[cp * 6 + n][r];
                b[r] = s / cntf;
            }
            const float wv = b[3];
            const float dw = (fabsf(wv) < EPSF) ? 1.f : wv;
#pragma unroll
            for (int r = 0; r < 3; ++r) xyz[r] += b[r] / dw;
        }
        float* op = out + (size_t)cell * OUTC;
        op[0] = xyz[0] * 0.5f; op[1] = xyz[1] * 0.5f; op[2] = xyz[2] * 0.5f;
    }

    // ---- Phase B: gather over compacted valid slots ----
    const int V = (int)__popcll(m);
    float a0 = 0.f, a1 = 0.f, a2 = 0.f, a3 = 0.f;

    for (int s = 0; s < V; ++s) {
        const int    o = sOff[s];
        const float4 w = sW[s];
        if (TR) {
            const float* bp = feat + (size_t)o + t * 4;
            const float4 f00 = *(const float4*)(bp);
            const float4 f01 = *(const float4*)(bp + CFC);
            const float4 f10 = *(const float4*)(bp + WFC * CFC);
            const float4 f11 = *(const float4*)(bp + WFC * CFC + CFC);
            a0 += w.x * f00.x + w.y * f01.x + w.z * f10.x + w.w * f11.x;
            a1 += w.x * f00.y + w.y * f01.y + w.z * f10.y + w.w * f11.y;
            a2 += w.x * f00.z + w.y * f01.z + w.z * f10.z + w.w * f11.z;
            a3 += w.x * f00.w + w.y * f01.w + w.z * f10.w + w.w * f11.w;
        } else {
#pragma unroll
            for (int c = 0; c < 4; ++c) {
                const float* bp = feat + (size_t)o + (size_t)(4 * t + c) * HWC;
                const float f00 = bp[0];
                const float f01 = bp[1];
                const float f10 = bp[WFC];
                const float f11 = bp[WFC + 1];
                const float r = w.x * f00 + w.y * f01 + w.z * f10 + w.w * f11;
                if (c == 0) a0 += r; else if (c == 1) a1 += r;
                else if (c == 2) a2 += r; else a3 += r;
            }
        }
    }

    float* op = out + (size_t)cell * OUTC + 3 + t * 4;
    op[0] = a0; op[1] = a1; op[2] = a2; op[3] = a3;
}

extern "C" void kernel_launch(void* const* d_in, const int* in_sizes, int n_in,
                              void* d_out, int out_size, void* d_ws, size_t ws_size,
                              hipStream_t stream)
{
    const float* points   = (const float*)d_in[0];
    const float* img_feat = (const float*)d_in[1];
    const float* lid2img  = (const float*)d_in[2];
    const float* ego2lid  = (const float*)d_in[3];
    const float* img2lid  = (const float*)d_in[4];
    const int*   img_h    = (const int*)d_in[5];
    const int*   img_w    = (const int*)d_in[6];
    float*       out      = (float*)d_out;

    const size_t need = (size_t)TN * CFC * HWC * sizeof(float);  // 17.3 MB
    const int    ncell = 128 * 128;

    if (ws_size >= need) {
        float* featT = (float*)d_ws;
        dim3 tg(HWC / 32, CFC / 32, TN);  // (88, 8, 6)
        proj_transpose_kernel<<<tg, dim3(32, 8), 0, stream>>>(img_feat, featT);
        proj_fuse_kernel<true><<<ncell, 64, 0, stream>>>(
            points, featT, lid2img, ego2lid, img2lid, img_h, img_w, out);
    } else {
        proj_fuse_kernel<false><<<ncell, 64, 0, stream>>>(
            points, img_feat, lid2img, ego2lid, img2lid, img_h, img_w, out);
    }
}